// Round 11
// baseline (604.213 us; speedup 1.0000x reference)
//
#include <hip/hip_runtime.h>
#include <hip/hip_bf16.h>

#define T_TOK 8192
#define DIM   1024
#define HID   4096
#define NE    8
#define RCAP  (T_TOK * 2 + 256)

typedef unsigned short u16;
typedef unsigned int   u32;
typedef float  f32x4 __attribute__((ext_vector_type(4)));
typedef __bf16 bf16x8 __attribute__((ext_vector_type(8)));

__device__ __forceinline__ u16 f2bf(float f) {
    u32 u = __builtin_bit_cast(u32, f);
    return (u16)((u + 0x7FFFu + ((u >> 16) & 1u)) >> 16);
}
__device__ __forceinline__ u32 pk2(float a, float b) {
    return (u32)f2bf(a) | ((u32)f2bf(b) << 16);
}

#define GLOAD_LDS16(g, l) \
    __builtin_amdgcn_global_load_lds((const __attribute__((address_space(1))) u32*)(g), \
                                     (__attribute__((address_space(3))) u32*)(l), 16, 0, 0)

// ---------------- router: one wave per token; counters padded (1/line) ----------------
__global__ __launch_bounds__(256) void router_kernel(
    const float* __restrict__ x, const float* __restrict__ gw,
    int* __restrict__ tok_e, float* __restrict__ tok_w, int* __restrict__ cnt)
{
    int wid  = threadIdx.x >> 6;
    int lane = threadIdx.x & 63;
    int t = blockIdx.x * 4 + wid;

    const float4* xp = (const float4*)(x + (size_t)t * DIM);
    float4 xv[4];
    #pragma unroll
    for (int c = 0; c < 4; ++c) xv[c] = xp[c * 64 + lane];

    float r[NE];
    #pragma unroll
    for (int e = 0; e < NE; ++e) {
        const float4* gp = (const float4*)(gw + e * DIM);
        float acc = 0.f;
        #pragma unroll
        for (int c = 0; c < 4; ++c) {
            float4 g = gp[c * 64 + lane];
            acc += xv[c].x * g.x + xv[c].y * g.y + xv[c].z * g.z + xv[c].w * g.w;
        }
        r[e] = acc;
    }
    #pragma unroll
    for (int s = 1; s < 64; s <<= 1) {
        #pragma unroll
        for (int e = 0; e < NE; ++e) r[e] += __shfl_xor(r[e], s);
    }
    if (lane == 0) {
        int e0 = 0; float l0 = r[0];
        #pragma unroll
        for (int e = 1; e < NE; ++e) if (r[e] > l0) { l0 = r[e]; e0 = e; }
        int e1 = -1; float l1 = -3e38f;
        #pragma unroll
        for (int e = 0; e < NE; ++e) if (e != e0 && r[e] > l1) { l1 = r[e]; e1 = e; }
        float d  = __expf(l1 - l0);          // <= 1
        float w0 = 1.f / (1.f + d);
        float w1 = d * w0;
        tok_e[t * 2]     = e0;  tok_e[t * 2 + 1] = e1;
        tok_w[t * 2]     = w0;  tok_w[t * 2 + 1] = w1;
        atomicAdd(&cnt[e0 * 16], 1);
        atomicAdd(&cnt[e1 * 16], 1);
    }
}

// ---------------- prefix: bases + 128-tile cumsums ----------------
__global__ void prefix_kernel(const int* __restrict__ cnt, int* __restrict__ base,
                              int* __restrict__ qmeta)
{
    if (threadIdx.x == 0) {
        int* cmts = qmeta;        // [9] cumulative 128-row M-tiles
        int s = 0, c = 0;
        cmts[0] = 0;
        for (int e = 0; e < NE; ++e) {
            base[e] = s; s += cnt[e * 16];
            c += (cnt[e * 16] + 127) >> 7;
            cmts[e + 1] = c;
        }
        qmeta[32] = 0;   // qcur1
        qmeta[33] = 0;   // qcur2
    }
}

// ---------------- scatter: 32 tokens/block, LDS ranks, 8 padded atomics/block ----------------
__global__ __launch_bounds__(256) void scatter_kernel(
    const float* __restrict__ x, const int* __restrict__ tok_e,
    const int* __restrict__ base, int* __restrict__ cursor,
    int* __restrict__ invrow, u16* __restrict__ A1)
{
    __shared__ int hist[NE], gbase[NE], rows[64];
    int b  = blockIdx.x;
    int t0 = b * 32;
    if (threadIdx.x < NE) hist[threadIdx.x] = 0;
    __syncthreads();
    if (threadIdx.x == 0) {
        for (int s = 0; s < 64; ++s) {
            int e = tok_e[t0 * 2 + s];
            rows[s] = hist[e]++;
        }
        for (int e = 0; e < NE; ++e)
            gbase[e] = atomicAdd(&cursor[e * 16], hist[e]);
        for (int s = 0; s < 64; ++s) {
            int e = tok_e[t0 * 2 + s];
            int row = base[e] + gbase[e] + rows[s];
            rows[s] = row;
            invrow[t0 * 2 + s] = row;
        }
    }
    __syncthreads();
    int i = threadIdx.x;
    for (int t = 0; t < 32; ++t) {
        float4 xv = ((const float4*)(x + (size_t)(t0 + t) * DIM))[i];
        u32 p0 = pk2(xv.x, xv.y);
        u32 p1 = pk2(xv.z, xv.w);
        int r0 = rows[2 * t], r1 = rows[2 * t + 1];
        u32* d0 = (u32*)(A1 + (size_t)r0 * DIM) + i * 2;
        d0[0] = p0; d0[1] = p1;
        u32* d1 = (u32*)(A1 + (size_t)r1 * DIM) + i * 2;
        d1[0] = p0; d1[1] = p1;
    }
}

// ---------------- fp32 -> bf16 weight conversion ----------------
__global__ __launch_bounds__(256) void convw_kernel(
    const float* __restrict__ W1, const float* __restrict__ W2,
    u16* __restrict__ W1b, u16* __restrict__ W2b)
{
    const size_t n8 = (size_t)NE * HID * DIM / 8;
    size_t stride = (size_t)gridDim.x * blockDim.x;
    for (size_t i = blockIdx.x * (size_t)blockDim.x + threadIdx.x; i < 2 * n8; i += stride) {
        const float* src = (i < n8) ? W1 : W2;
        u16*         dst = (i < n8) ? W1b : W2b;
        size_t j = (i < n8) ? i : i - n8;
        float4 a = ((const float4*)src)[j * 2];
        float4 b = ((const float4*)src)[j * 2 + 1];
        uint4 o;
        o.x = pk2(a.x, a.y); o.y = pk2(a.z, a.w);
        o.z = pk2(b.x, b.y); o.w = pk2(b.z, b.w);
        ((uint4*)dst)[j] = o;
    }
}

// ---------------- persistent grouped GEMM, m97 structure ----------------
// 128x128 tile, BK=64, 4 waves (2x2, 64x64 per wave), single 32 KB LDS buffer,
// plain 2-__syncthreads loop, ~3 blocks/CU (TLP hides barrier drain, m114).
// LDS swizzle for 128-B rows: read 16B-group g at row r -> g^(r&7); staging
// global source col-group (tid&7)^((tid>>3)&7) (same involution, rule #21).
// Queue at 128-tile granularity; nt-inner for A-panel reuse. G2 split-K=2.
template<int KDIM, int NDIM, bool IS_G2>
__global__ __launch_bounds__(256, 3) void moe_gemm(
    const u16* __restrict__ A, const u16* __restrict__ B,
    const float* __restrict__ bias,
    u16* __restrict__ Hout, float* __restrict__ Y0, float* __restrict__ Y1,
    const int* __restrict__ cnt, const int* __restrict__ base,
    const int* __restrict__ cmts, int* __restrict__ qcur)
{
    constexpr int KLEN = IS_G2 ? (KDIM / 2) : KDIM;
    constexpr int NKT  = KLEN / 64;           // 16 (G1) / 32 (G2)
    constexpr int NTN  = NDIM / 128;          // 32 (G1) / 8 (G2)

    __shared__ u16 As[128 * 64];              // 16 KB
    __shared__ u16 Bs[128 * 64];              // 16 KB
    __shared__ int sitem;

    int tid  = threadIdx.x;
    int lane = tid & 63;
    int w    = tid >> 6;
    int wr   = w >> 1, wc = w & 1;

    // staging: slot s = rd*256 + tid; LDS dst = s*16 B; src row = s>>3, swizzled col
    int srow = tid >> 3;                      // 0..31 per round
    int scol = (((tid & 7) ^ ((tid >> 3) & 7)) * 8);
    u16* dA = As + tid * 8;
    u16* dB = Bs + tid * 8;

    int M1    = cmts[NE];
    int total = M1 * NTN * (IS_G2 ? 2 : 1);

    for (;;) {
        __syncthreads();                      // drains stores; protects sitem/LDS
        if (tid == 0) {
            int p = atomicAdd(qcur, 1);
            int it = -1;
            if (p < total) {
                int mtg, nt, ks = 0;
                if (IS_G2) { mtg = p >> 4; ks = (p >> 3) & 1; nt = p & 7; }
                else       { mtg = p >> 5; nt = p & 31; }
                int e = 0;
                while (mtg >= cmts[e + 1]) ++e;
                int mt = mtg - cmts[e];
                it = (e << 20) | (ks << 16) | (nt << 8) | mt;
            }
            sitem = it;
        }
        __syncthreads();
        int item = sitem;
        if (item < 0) break;

        int e  = item >> 20;
        int ks = (item >> 16) & 15;
        int nt = (item >> 8) & 255;
        int mt = item & 255;
        int ce = cnt[e * 16];
        int m0 = base[e] + mt * 128;
        int n0 = nt * 128;
        int k0 = ks * KLEN;

        const u16* aB = A + (size_t)(m0 + srow) * KDIM + k0 + scol;
        const u16* bB = B + (size_t)e * NDIM * KDIM + (size_t)(n0 + srow) * KDIM + k0 + scol;

        f32x4 acc[4][4];
        #pragma unroll
        for (int m = 0; m < 4; ++m)
            #pragma unroll
            for (int n = 0; n < 4; ++n)
                #pragma unroll
                for (int i = 0; i < 4; ++i) acc[m][n][i] = 0.f;

        for (int kt = 0; kt < NKT; ++kt) {
            // stage tile kt (8 x 16B per thread)
            #pragma unroll
            for (int rd = 0; rd < 4; ++rd) {
                GLOAD_LDS16(aB + (size_t)kt * 64 + (size_t)rd * 32 * KDIM, dA + rd * 2048);
                GLOAD_LDS16(bB + (size_t)kt * 64 + (size_t)rd * 32 * KDIM, dB + rd * 2048);
            }
            __syncthreads();                  // vmcnt drained -> tile ready
            #pragma unroll
            for (int kk = 0; kk < 2; ++kk) {
                int g = (lane >> 4) + 4 * kk;
                bf16x8 af[4], bv[4];
                #pragma unroll
                for (int m = 0; m < 4; ++m) {
                    int r = wr * 64 + m * 16 + (lane & 15);
                    af[m] = *(const bf16x8*)(As + r * 64 + ((g ^ (r & 7)) * 8));
                }
                #pragma unroll
                for (int n = 0; n < 4; ++n) {
                    int r = wc * 64 + n * 16 + (lane & 15);
                    bv[n] = *(const bf16x8*)(Bs + r * 64 + ((g ^ (r & 7)) * 8));
                }
                #pragma unroll
                for (int m = 0; m < 4; ++m)
                    #pragma unroll
                    for (int n = 0; n < 4; ++n)
                        acc[m][n] = __builtin_amdgcn_mfma_f32_16x16x32_bf16(af[m], bv[n], acc[m][n], 0, 0, 0);
            }
            __syncthreads();                  // all reads done before overwrite
        }

        // epilogue: C/D layout col = lane&15, row = (lane>>4)*4 + reg
        #pragma unroll
        for (int m = 0; m < 4; ++m) {
            #pragma unroll
            for (int j = 0; j < 4; ++j) {
                int rr   = wr * 64 + m * 16 + (lane >> 4) * 4 + j;
                int rloc = mt * 128 + rr;
                if (rloc < ce) {
                    if (!IS_G2) {
                        u16* hp = Hout + (size_t)(m0 + rr) * NDIM;
                        #pragma unroll
                        for (int n = 0; n < 4; ++n) {
                            int gcol = n0 + wc * 64 + n * 16 + (lane & 15);
                            float v = acc[m][n][j] + bias[e * NDIM + gcol];
                            v = v > 0.f ? v : 0.f;
                            hp[gcol] = f2bf(v);
                        }
                    } else {
                        float* yp = (ks == 0 ? Y0 : Y1) + (size_t)(m0 + rr) * NDIM;
                        #pragma unroll
                        for (int n = 0; n < 4; ++n) {
                            int gcol = n0 + wc * 64 + n * 16 + (lane & 15);
                            float v = acc[m][n][j];
                            if (ks == 0) v += bias[e * NDIM + gcol];
                            yp[gcol] = v;
                        }
                    }
                }
            }
        }
    }
}

// ---------------- combine: out[t] = w0*(Y0[r0]+Y1[r0]) + w1*(Y0[r1]+Y1[r1]) ----------------
__global__ __launch_bounds__(256) void combine_kernel(
    const float* __restrict__ Y0, const float* __restrict__ Y1,
    const int* __restrict__ invrow, const float* __restrict__ tok_w,
    float* __restrict__ out)
{
    int t  = blockIdx.x;
    int r0 = invrow[t * 2], r1 = invrow[t * 2 + 1];
    float w0 = tok_w[t * 2], w1 = tok_w[t * 2 + 1];
    int i = threadIdx.x;
    float4 a0 = ((const float4*)(Y0 + (size_t)r0 * DIM))[i];
    float4 b0 = ((const float4*)(Y1 + (size_t)r0 * DIM))[i];
    float4 a1 = ((const float4*)(Y0 + (size_t)r1 * DIM))[i];
    float4 b1 = ((const float4*)(Y1 + (size_t)r1 * DIM))[i];
    float4 o;
    o.x = w0 * (a0.x + b0.x) + w1 * (a1.x + b1.x);
    o.y = w0 * (a0.y + b0.y) + w1 * (a1.y + b1.y);
    o.z = w0 * (a0.z + b0.z) + w1 * (a1.z + b1.z);
    o.w = w0 * (a0.w + b0.w) + w1 * (a1.w + b1.w);
    ((float4*)(out + (size_t)t * DIM))[i] = o;
}

extern "C" void kernel_launch(void* const* d_in, const int* in_sizes, int n_in,
                              void* d_out, int out_size, void* d_ws, size_t ws_size,
                              hipStream_t stream) {
    const float* xs = (const float*)d_in[0];
    const float* gw = (const float*)d_in[1];
    const float* W1 = (const float*)d_in[2];
    const float* b1 = (const float*)d_in[3];
    const float* W2 = (const float*)d_in[4];
    const float* b2 = (const float*)d_in[5];
    float* out = (float*)d_out;

    char* ws = (char*)d_ws;
    size_t off = 0;
    auto alloc = [&](size_t bytes) -> void* {
        off = (off + 255) & ~(size_t)255;
        void* p = ws + off;
        off += bytes;
        return p;
    };
    int*   ctrs   = (int*)alloc(2048);          // cnt[e*16] @0, cursor[e*16] @+128 ints
    int*   cnt    = ctrs;
    int*   cursor = ctrs + 128;
    int*   base   = (int*)alloc(64);
    int*   qmeta  = (int*)alloc(256);           // cmts[9], qcur@32,33
    int*   tok_e  = (int*)alloc((size_t)T_TOK * 2 * 4);
    float* tok_w  = (float*)alloc((size_t)T_TOK * 2 * 4);
    int*   invrow = (int*)alloc((size_t)T_TOK * 2 * 4);
    u16*   A1     = (u16*)alloc((size_t)RCAP * DIM * 2);       // 34 MB
    u16*   W1b    = (u16*)alloc((size_t)NE * HID * DIM * 2);   // 64 MB
    u16*   W2b    = (u16*)alloc((size_t)NE * HID * DIM * 2);   // 64 MB
    u16*   hbuf   = (u16*)alloc((size_t)RCAP * HID * 2);       // 136 MB
    float* Ypart0 = (float*)alloc((size_t)T_TOK * 2 * DIM * 4);// 64 MB
    float* Ypart1 = (float*)A1;   // alias A1+W1b (both dead during GEMM2/combine)
    (void)ws_size; (void)in_sizes; (void)n_in; (void)out_size;

    hipMemsetAsync(ctrs, 0, 2048, stream);

    router_kernel<<<T_TOK / 4, 256, 0, stream>>>(xs, gw, tok_e, tok_w, cnt);
    prefix_kernel<<<1, 64, 0, stream>>>(cnt, base, qmeta);
    scatter_kernel<<<T_TOK / 32, 256, 0, stream>>>(xs, tok_e, base, cursor, invrow, A1);
    convw_kernel<<<2048, 256, 0, stream>>>(W1, W2, W1b, W2b);

    moe_gemm<DIM, HID, false><<<768, 256, 0, stream>>>(
        A1, W1b, b1, hbuf, nullptr, nullptr, cnt, base, qmeta, qmeta + 32);
    moe_gemm<HID, DIM, true><<<768, 256, 0, stream>>>(
        hbuf, W2b, b2, nullptr, Ypart0, Ypart1, cnt, base, qmeta, qmeta + 33);

    combine_kernel<<<T_TOK, 256, 0, stream>>>(Ypart0, Ypart1, invrow, tok_w, out);
}